// Round 1
// baseline (49.272 us; speedup 1.0000x reference)
//
#include <hip/hip_runtime.h>
#include <math.h>

#define NEAR_F 2.0f
#define FAR_F 6.0f
#define FAR_DIST_F 1e10f

constexpr int N_RAYS = 65536;
constexpr int S = 128;
constexpr int NBLK = 2048;   // 2048 blocks * 4 waves = 8192 waves = device capacity

__global__ __launch_bounds__(256) void integrate_kernel(
    const float* __restrict__ raw,     // [N][128][4]
    const float* __restrict__ zvals,   // [N][128]
    const float* __restrict__ rays_d,  // [N][3]
    float* __restrict__ chs_map,       // [N][3]
    float* __restrict__ depth_map,     // [N]
    float* __restrict__ block_partials) // [gridDim.x]
{
    const int lane = threadIdx.x & 63;
    const int warp = threadIdx.x >> 6;

    float ent_acc = 0.0f;   // only meaningful on lane 0 of each wave

    for (int ray = blockIdx.x * 4 + warp; ray < N_RAYS; ray += NBLK * 4) {
        // ray direction norm (same address across lanes -> broadcast fetch)
        const float dx = rays_d[(size_t)ray * 3 + 0];
        const float dy = rays_d[(size_t)ray * 3 + 1];
        const float dz = rays_d[(size_t)ray * 3 + 2];
        const float norm = sqrtf(dx * dx + dy * dy + dz * dz);

        // zvals: lane l holds samples l and l+64
        const float* zr = zvals + (size_t)ray * S;
        const float z0 = zr[lane];
        const float z1 = zr[lane + 64];

        // neighbor z for dists
        float z0_next = __shfl(z0, (lane + 1) & 63);
        const float z1_lane0 = __shfl(z1, 0);
        if (lane == 63) z0_next = z1_lane0;
        const float z1_next = __shfl(z1, (lane + 1) & 63);

        const float dist0 = (z0_next - z0) * norm;
        const float dist1 = (lane == 63) ? (FAR_DIST_F * norm) : ((z1_next - z1) * norm);

        // raw: float4 per sample (rgb + sigma)
        const float4* rr = (const float4*)(raw + (size_t)ray * S * 4);
        const float4 r0 = rr[lane];
        const float4 r1 = rr[lane + 64];

        const float sig0 = fmaxf(r0.w, 0.0f);
        const float sig1 = fmaxf(r1.w, 0.0f);
        const float alpha0 = 1.0f - expf(-sig0 * dist0);
        const float alpha1 = 1.0f - expf(-sig1 * dist1);
        const float t0 = 1.0f - alpha0 + 1e-10f;
        const float t1 = 1.0f - alpha1 + 1e-10f;

        // inclusive prefix product of t0 across 64 lanes
        float p0 = t0;
        #pragma unroll
        for (int d = 1; d < 64; d <<= 1) {
            const float v = __shfl_up(p0, d);
            if (lane >= d) p0 *= v;
        }
        float trans0 = __shfl_up(p0, 1);
        if (lane == 0) trans0 = 1.0f;
        const float total0 = __shfl(p0, 63);

        float p1 = t1;
        #pragma unroll
        for (int d = 1; d < 64; d <<= 1) {
            const float v = __shfl_up(p1, d);
            if (lane >= d) p1 *= v;
        }
        float e1 = __shfl_up(p1, 1);
        if (lane == 0) e1 = 1.0f;
        const float trans1 = total0 * e1;

        const float w0 = alpha0 * trans0;
        const float w1 = alpha1 * trans1;

        const float zn0 = (FAR_F - z0) * (1.0f / (FAR_F - NEAR_F));
        const float zn1 = (FAR_F - z1) * (1.0f / (FAR_F - NEAR_F));

        float c0 = w0 * r0.x + w1 * r1.x;
        float c1 = w0 * r0.y + w1 * r1.y;
        float c2 = w0 * r0.z + w1 * r1.z;
        float wsum = w0 + w1;
        float dnum = w0 * zn0 + w1 * zn1;
        float a = (w0 > 0.0f ? w0 * logf(w0) : 0.0f)
                + (w1 > 0.0f ? w1 * logf(w1) : 0.0f);

        // butterfly reduce the 6 scalars across the wave
        #pragma unroll
        for (int m = 32; m >= 1; m >>= 1) {
            c0   += __shfl_xor(c0, m);
            c1   += __shfl_xor(c1, m);
            c2   += __shfl_xor(c2, m);
            wsum += __shfl_xor(wsum, m);
            dnum += __shfl_xor(dnum, m);
            a    += __shfl_xor(a, m);
        }

        if (lane == 0) {
            chs_map[(size_t)ray * 3 + 0] = c0;
            chs_map[(size_t)ray * 3 + 1] = c1;
            chs_map[(size_t)ray * 3 + 2] = c2;
            depth_map[ray] = dnum / (wsum + 1e-5f);

            // entropy: sum p*log p = (A - W*log(psum) + L*(log L - log psum)) / psum
            const float L = 1.0f - wsum + 1e-6f;
            const float psum = wsum + L;
            const float logpsum = logf(psum);
            const float entL = (L > 0.0f) ? L * (logf(L) - logpsum) : 0.0f;
            const float ent = (a - wsum * logpsum + entL) / psum;
            ent_acc -= ent;
        }
    }

    // block-level combine of per-wave entropy partials
    __shared__ float sred[4];
    if (lane == 0) sred[warp] = ent_acc;
    __syncthreads();
    if (threadIdx.x == 0) {
        float s = 0.0f;
        #pragma unroll
        for (int i = 0; i < 4; ++i) s += sred[i];
        block_partials[blockIdx.x] = s;
    }
}

__global__ __launch_bounds__(256) void reduce_kernel(
    const float* __restrict__ partials, int n, float* __restrict__ out_scalar)
{
    float s = 0.0f;
    for (int i = threadIdx.x; i < n; i += 256) s += partials[i];
    #pragma unroll
    for (int m = 32; m >= 1; m >>= 1) s += __shfl_xor(s, m);
    __shared__ float sr[4];
    const int lane = threadIdx.x & 63;
    const int warp = threadIdx.x >> 6;
    if (lane == 0) sr[warp] = s;
    __syncthreads();
    if (threadIdx.x == 0) {
        float t = 0.0f;
        #pragma unroll
        for (int i = 0; i < 4; ++i) t += sr[i];
        *out_scalar = t;
    }
}

extern "C" void kernel_launch(void* const* d_in, const int* in_sizes, int n_in,
                              void* d_out, int out_size, void* d_ws, size_t ws_size,
                              hipStream_t stream) {
    const float* raw    = (const float*)d_in[0];
    const float* zvals  = (const float*)d_in[1];
    const float* rays_d = (const float*)d_in[2];

    float* out = (float*)d_out;
    float* chs_map   = out;                       // 65536*3
    float* depth_map = out + (size_t)N_RAYS * 3;  // 65536
    float* sparsity  = out + (size_t)N_RAYS * 4;  // 1

    float* partials = (float*)d_ws;               // NBLK floats (8 KiB)

    integrate_kernel<<<NBLK, 256, 0, stream>>>(raw, zvals, rays_d,
                                               chs_map, depth_map, partials);
    reduce_kernel<<<1, 256, 0, stream>>>(partials, NBLK, sparsity);
}

// Round 2
// 35.965 us; speedup vs baseline: 1.3700x; 1.3700x over previous
//
#include <hip/hip_runtime.h>
#include <math.h>

constexpr int N_RAYS = 65536;
constexpr int NBLK   = 2048;     // 2048 blocks * 4 waves = 8192 waves
constexpr int WAVES  = NBLK * 4; // device wave capacity

// One wave handles 4 rays (16 lanes per ray). Each lane owns 4 consecutive
// samples per 64-sample half; transmittance carried across halves.
__global__ __launch_bounds__(256) void integrate_kernel(
    const float* __restrict__ raw,     // [N][128][4]
    const float* __restrict__ zvals,   // [N][128]
    const float* __restrict__ rays_d,  // [N][3]
    float* __restrict__ chs_map,       // [N][3]
    float* __restrict__ depth_map,     // [N]
    float* __restrict__ block_partials)
{
    const int lane = threadIdx.x & 63;
    const int warp = threadIdx.x >> 6;
    const int g    = lane >> 4;   // ray group within wave (0..3)
    const int m    = lane & 15;   // lane within group

    // per-warp staging: 4 rays x 64 samples (half) x float4, +1 float4 row pad
    __shared__ float4 sraw[4][4][65];

    float ent_acc = 0.0f;

    const int gw = blockIdx.x * 4 + warp;   // global wave id 0..8191

    #pragma unroll
    for (int k = 0; k < 2; ++k) {
        const int ray0 = (gw + k * WAVES) * 4;  // first of this wave's 4 rays
        const int ray  = ray0 + g;

        // ray norm (16 lanes read same 3 floats -> broadcast)
        const float* rd = rays_d + (size_t)ray * 3;
        const float norm = sqrtf(rd[0]*rd[0] + rd[1]*rd[1] + rd[2]*rd[2]);

        // zvals: lane owns samples 4m..4m+3 (half0) and 64+4m..64+4m+3 (half1)
        const float* zr = zvals + (size_t)ray * 128;
        const float4 zA4 = *(const float4*)(zr + 4*m);
        const float4 zB4 = *(const float4*)(zr + 64 + 4*m);
        float za[4] = {zA4.x, zA4.y, zA4.z, zA4.w};
        float zb[4] = {zB4.x, zB4.y, zB4.z, zB4.w};

        // neighbor z for the last sample of each lane
        const float nA  = __shfl_down(za[0], 1, 16);  // z[4m+4]
        const float nB  = __shfl_down(zb[0], 1, 16);  // z[64+4m+4]
        const float z64 = __shfl(zb[0], 0, 16);       // z[64] (group lane 0)

        float c0=0.f, c1=0.f, c2=0.f, wsum=0.f, dnum=0.f, aa=0.f;
        float carry = 1.0f;

        const float4* rbase = (const float4*)raw + (size_t)ray0 * 128;

        #pragma unroll
        for (int h = 0; h < 2; ++h) {
            // ---- stage this half's raw into LDS, fully coalesced (1KiB/instr)
            #pragma unroll
            for (int rr = 0; rr < 4; ++rr)
                sraw[warp][rr][lane] = rbase[rr*128 + h*64 + lane];
            // same-wave write->read through LDS: instruction-stream ordered,
            // compiler inserts lgkmcnt waits (no barrier needed; per-warp slice)

            float4 q[4];
            #pragma unroll
            for (int j = 0; j < 4; ++j)
                q[j] = sraw[warp][g][4*m + j];

            // per-sample z and dist (compile-time h select)
            float zc[4], dd[4];
            #pragma unroll
            for (int j = 0; j < 4; ++j) zc[j] = (h == 0) ? za[j] : zb[j];
            #pragma unroll
            for (int j = 0; j < 3; ++j) dd[j] = zc[j+1] - zc[j];
            if (h == 0) dd[3] = ((m == 15) ? z64 : nA) - zc[3];
            else        dd[3] = (m == 15) ? 1e10f : (nB - zc[3]);
            #pragma unroll
            for (int j = 0; j < 4; ++j) dd[j] *= norm;

            // alpha / t, local prefix product
            float alpha[4], tt[4];
            #pragma unroll
            for (int j = 0; j < 4; ++j) {
                const float sig = fmaxf(q[j].w, 0.0f);
                alpha[j] = 1.0f - __expf(-sig * dd[j]);
                tt[j]    = 1.0f - alpha[j] + 1e-10f;
            }
            float P = tt[0] * tt[1] * tt[2] * tt[3];

            // inclusive scan of P across 16 lanes
            float sc = P;
            #pragma unroll
            for (int d = 1; d < 16; d <<= 1) {
                const float v = __shfl_up(sc, d, 16);
                if (m >= d) sc *= v;
            }
            float E = __shfl_up(sc, 1, 16);
            if (m == 0) E = 1.0f;
            const float tot = __shfl(sc, 15, 16);

            // weights + accumulation
            float trj = carry * E;
            #pragma unroll
            for (int j = 0; j < 4; ++j) {
                const float w = alpha[j] * trj;
                c0   += w * q[j].x;
                c1   += w * q[j].y;
                c2   += w * q[j].z;
                wsum += w;
                dnum += w * (6.0f - zc[j]) * 0.25f;
                aa   += (w > 0.0f) ? w * __logf(w) : 0.0f;
                trj  *= tt[j];
            }
            carry *= tot;
        }

        // butterfly allreduce within the 16-lane group (4 steps x 6 vars)
        #pragma unroll
        for (int d = 1; d < 16; d <<= 1) {
            c0   += __shfl_xor(c0,   d, 16);
            c1   += __shfl_xor(c1,   d, 16);
            c2   += __shfl_xor(c2,   d, 16);
            wsum += __shfl_xor(wsum, d, 16);
            dnum += __shfl_xor(dnum, d, 16);
            aa   += __shfl_xor(aa,   d, 16);
        }

        if (m == 0) {
            chs_map[(size_t)ray * 3 + 0] = c0;
            chs_map[(size_t)ray * 3 + 1] = c1;
            chs_map[(size_t)ray * 3 + 2] = c2;
            depth_map[ray] = dnum / (wsum + 1e-5f);

            // sum p*log p = (A - W*log(psum) + L*(log L - log psum)) / psum
            const float L = 1.0f - wsum + 1e-6f;
            const float psum = wsum + L;
            const float logpsum = __logf(psum);
            const float entL = (L > 0.0f) ? L * (__logf(L) - logpsum) : 0.0f;
            ent_acc -= (aa - wsum * logpsum + entL) / psum;
        }
    }

    // entropy: full-wave reduce (non-leaders hold 0), then block combine
    #pragma unroll
    for (int d = 1; d < 64; d <<= 1)
        ent_acc += __shfl_xor(ent_acc, d);

    __shared__ float sred[4];
    if (lane == 0) sred[warp] = ent_acc;
    __syncthreads();
    if (threadIdx.x == 0) {
        float s = 0.0f;
        #pragma unroll
        for (int i = 0; i < 4; ++i) s += sred[i];
        block_partials[blockIdx.x] = s;
    }
}

__global__ __launch_bounds__(256) void reduce_kernel(
    const float* __restrict__ partials, int n, float* __restrict__ out_scalar)
{
    float s = 0.0f;
    for (int i = threadIdx.x; i < n; i += 256) s += partials[i];
    #pragma unroll
    for (int mm = 32; mm >= 1; mm >>= 1) s += __shfl_xor(s, mm);
    __shared__ float sr[4];
    const int lane = threadIdx.x & 63;
    const int warp = threadIdx.x >> 6;
    if (lane == 0) sr[warp] = s;
    __syncthreads();
    if (threadIdx.x == 0) {
        float t = 0.0f;
        #pragma unroll
        for (int i = 0; i < 4; ++i) t += sr[i];
        *out_scalar = t;
    }
}

extern "C" void kernel_launch(void* const* d_in, const int* in_sizes, int n_in,
                              void* d_out, int out_size, void* d_ws, size_t ws_size,
                              hipStream_t stream) {
    const float* raw    = (const float*)d_in[0];
    const float* zvals  = (const float*)d_in[1];
    const float* rays_d = (const float*)d_in[2];

    float* out = (float*)d_out;
    float* chs_map   = out;                       // 65536*3
    float* depth_map = out + (size_t)N_RAYS * 3;  // 65536
    float* sparsity  = out + (size_t)N_RAYS * 4;  // 1

    float* partials = (float*)d_ws;               // NBLK floats

    integrate_kernel<<<NBLK, 256, 0, stream>>>(raw, zvals, rays_d,
                                               chs_map, depth_map, partials);
    reduce_kernel<<<1, 256, 0, stream>>>(partials, NBLK, sparsity);
}

// Round 3
// 34.304 us; speedup vs baseline: 1.4363x; 1.0484x over previous
//
#include <hip/hip_runtime.h>
#include <math.h>

constexpr int N_RAYS = 65536;
constexpr int NBLK   = 2048;     // 2048 blocks * 4 waves = 8192 waves
constexpr int WAVES  = NBLK * 4;

// DPP move: result = dpp(src) for valid source lanes, else `oldv`.
// CTRL: 0x00-0xFF quad_perm, 0x110+n row_shr:n, 0x100+n row_shl:n,
//       0x140 row_mirror, 0x141 row_half_mirror. Rows are 16 lanes.
template<int CTRL>
__device__ __forceinline__ float dpp_movf(float x, float oldv) {
    return __int_as_float(__builtin_amdgcn_update_dpp(
        __float_as_int(oldv), __float_as_int(x), CTRL, 0xF, 0xF, false));
}

// 4-step butterfly sum over each 16-lane row (pure VALU, no DS traffic)
__device__ __forceinline__ float row16_sum(float x) {
    x += dpp_movf<0xB1>(x, 0.0f);   // quad_perm(1,0,3,2)
    x += dpp_movf<0x4E>(x, 0.0f);   // quad_perm(2,3,0,1)
    x += dpp_movf<0x141>(x, 0.0f);  // row_half_mirror
    x += dpp_movf<0x140>(x, 0.0f);  // row_mirror
    return x;
}

// One wave = 4 rays (16 lanes/ray). Lane owns 4 consecutive samples per
// 64-sample half; transmittance carried across halves. No LDS staging:
// direct per-lane float4 loads. All cross-lane ops are DPP except one
// __shfl per ray-half carry.
__global__ __launch_bounds__(256) void integrate_kernel(
    const float* __restrict__ raw,     // [N][128][4]
    const float* __restrict__ zvals,   // [N][128]
    const float* __restrict__ rays_d,  // [N][3]
    float* __restrict__ chs_map,       // [N][3]
    float* __restrict__ depth_map,     // [N]
    float* __restrict__ block_partials)
{
    const int lane = threadIdx.x & 63;
    const int warp = threadIdx.x >> 6;
    const int g    = lane >> 4;   // ray within wave
    const int m    = lane & 15;   // lane within ray group

    float ent_acc = 0.0f;
    const int gw = blockIdx.x * 4 + warp;

    #pragma unroll
    for (int k = 0; k < 2; ++k) {
        const int ray = (gw + k * WAVES) * 4 + g;

        // ray norm (16 lanes same address -> broadcast fetch)
        const float* rd = rays_d + (size_t)ray * 3;
        const float norm = sqrtf(rd[0]*rd[0] + rd[1]*rd[1] + rd[2]*rd[2]);

        // zvals: float4 + one neighbor scalar per half (same cache lines)
        const float* zr = zvals + (size_t)ray * 128;
        const float4 zA  = *(const float4*)(zr + 4*m);
        const float4 zB  = *(const float4*)(zr + 64 + 4*m);
        const float znx0 = zr[4*m + 4];                        // m==15 -> z[64]
        const float znx1 = zr[(m == 15) ? 127 : (68 + 4*m)];   // m==15 unused

        // raw: 8 float4 per lane (64B contiguous per half), issued up-front
        const float4* rq = (const float4*)raw + (size_t)ray * 128;
        float4 q0[4], q1[4];
        #pragma unroll
        for (int j = 0; j < 4; ++j) q0[j] = rq[4*m + j];
        #pragma unroll
        for (int j = 0; j < 4; ++j) q1[j] = rq[64 + 4*m + j];

        float c0=0.f, c1=0.f, c2=0.f, wsum=0.f, dnum=0.f, aa=0.f;
        float carry = 1.0f;

        #pragma unroll
        for (int h = 0; h < 2; ++h) {
            float zc[5];
            float4 q[4];
            if (h == 0) {
                zc[0]=zA.x; zc[1]=zA.y; zc[2]=zA.z; zc[3]=zA.w; zc[4]=znx0;
                q[0]=q0[0]; q[1]=q0[1]; q[2]=q0[2]; q[3]=q0[3];
            } else {
                zc[0]=zB.x; zc[1]=zB.y; zc[2]=zB.z; zc[3]=zB.w; zc[4]=znx1;
                q[0]=q1[0]; q[1]=q1[1]; q[2]=q1[2]; q[3]=q1[3];
            }

            float dd[4];
            dd[0] = zc[1]-zc[0];
            dd[1] = zc[2]-zc[1];
            dd[2] = zc[3]-zc[2];
            dd[3] = (h == 1 && m == 15) ? 1e10f : (zc[4]-zc[3]);

            float alpha[4], tt[4];
            #pragma unroll
            for (int j = 0; j < 4; ++j) {
                const float sig = fmaxf(q[j].w, 0.0f);
                alpha[j] = 1.0f - __expf(-sig * dd[j] * norm);
                tt[j]    = 1.0f - alpha[j] + 1e-10f;
            }

            // inclusive product scan of per-lane product across the 16-row
            float p = tt[0]*tt[1]*tt[2]*tt[3];
            p *= dpp_movf<0x111>(p, 1.0f);  // row_shr:1
            p *= dpp_movf<0x112>(p, 1.0f);  // row_shr:2
            p *= dpp_movf<0x114>(p, 1.0f);  // row_shr:4
            p *= dpp_movf<0x118>(p, 1.0f);  // row_shr:8
            const float E = dpp_movf<0x111>(p, 1.0f);  // exclusive, lane0 -> 1

            float trj = carry * E;
            #pragma unroll
            for (int j = 0; j < 4; ++j) {
                const float w = alpha[j] * trj;
                c0   += w * q[j].x;
                c1   += w * q[j].y;
                c2   += w * q[j].z;
                wsum += w;
                dnum += w * (6.0f - zc[j]) * 0.25f;
                aa   += (w > 0.0f) ? w * __logf(w) : 0.0f;
                trj  *= tt[j];
            }
            if (h == 0) carry = __shfl(p, 15, 16);  // group total -> carry
        }

        // 6-var allreduce within the 16-lane group, pure DPP
        c0   = row16_sum(c0);
        c1   = row16_sum(c1);
        c2   = row16_sum(c2);
        wsum = row16_sum(wsum);
        dnum = row16_sum(dnum);
        aa   = row16_sum(aa);

        if (m == 0) {
            chs_map[(size_t)ray * 3 + 0] = c0;
            chs_map[(size_t)ray * 3 + 1] = c1;
            chs_map[(size_t)ray * 3 + 2] = c2;
            depth_map[ray] = dnum / (wsum + 1e-5f);

            // sum p*log p = (A - W*log(psum) + L*(log L - log psum)) / psum
            const float L = 1.0f - wsum + 1e-6f;
            const float psum = wsum + L;
            const float logpsum = __logf(psum);
            const float entL = (L > 0.0f) ? L * (__logf(L) - logpsum) : 0.0f;
            ent_acc -= (aa - wsum * logpsum + entL) / psum;
        }
    }

    // entropy partials live on lanes 0,16,32,48; wave reduce then block combine
    #pragma unroll
    for (int d = 1; d < 64; d <<= 1)
        ent_acc += __shfl_xor(ent_acc, d);

    __shared__ float sred[4];
    if (lane == 0) sred[warp] = ent_acc;
    __syncthreads();
    if (threadIdx.x == 0) {
        float s = 0.0f;
        #pragma unroll
        for (int i = 0; i < 4; ++i) s += sred[i];
        block_partials[blockIdx.x] = s;
    }
}

__global__ __launch_bounds__(256) void reduce_kernel(
    const float* __restrict__ partials, int n, float* __restrict__ out_scalar)
{
    float s = 0.0f;
    for (int i = threadIdx.x; i < n; i += 256) s += partials[i];
    #pragma unroll
    for (int mm = 32; mm >= 1; mm >>= 1) s += __shfl_xor(s, mm);
    __shared__ float sr[4];
    const int lane = threadIdx.x & 63;
    const int warp = threadIdx.x >> 6;
    if (lane == 0) sr[warp] = s;
    __syncthreads();
    if (threadIdx.x == 0) {
        float t = 0.0f;
        #pragma unroll
        for (int i = 0; i < 4; ++i) t += sr[i];
        *out_scalar = t;
    }
}

extern "C" void kernel_launch(void* const* d_in, const int* in_sizes, int n_in,
                              void* d_out, int out_size, void* d_ws, size_t ws_size,
                              hipStream_t stream) {
    const float* raw    = (const float*)d_in[0];
    const float* zvals  = (const float*)d_in[1];
    const float* rays_d = (const float*)d_in[2];

    float* out = (float*)d_out;
    float* chs_map   = out;                       // 65536*3
    float* depth_map = out + (size_t)N_RAYS * 3;  // 65536
    float* sparsity  = out + (size_t)N_RAYS * 4;  // 1

    float* partials = (float*)d_ws;               // NBLK floats

    integrate_kernel<<<NBLK, 256, 0, stream>>>(raw, zvals, rays_d,
                                               chs_map, depth_map, partials);
    reduce_kernel<<<1, 256, 0, stream>>>(partials, NBLK, sparsity);
}